// Round 9
// baseline (123.589 us; speedup 1.0000x reference)
//
#include <hip/hip_runtime.h>
#include <hip/hip_bf16.h>

#define BATCH 8
#define T 8192
#define IN_F 128
#define OUT_F 128
#define STATE_F 256
#define CHUNK 128
#define NCHUNK 64
#define ROWS 65536

typedef __attribute__((ext_vector_type(8))) short bf16x8;
typedef __attribute__((ext_vector_type(4))) float f32x4;

__device__ __forceinline__ float bflo(unsigned u) { return __uint_as_float(u << 16); }
__device__ __forceinline__ float bfhi(unsigned u) { return __uint_as_float(u & 0xffff0000u); }
__device__ __forceinline__ unsigned f2bfu(float f) {
    unsigned u = __float_as_uint(f);
    return (u + 0x7fffu + ((u >> 16) & 1u)) >> 16;
}
__device__ __forceinline__ unsigned packbf(float lo, float hi) {
    return f2bfu(lo) | (f2bfu(hi) << 16);
}

// ---------------------------------------------------------------------------
// kcvt: x fp32 -> bf16 (row-major [ROWS][128])
__global__ __launch_bounds__(256) void kcvt(const float* __restrict__ x,
                                            unsigned short* __restrict__ xbf) {
    int i0 = blockIdx.x * 256 + threadIdx.x;
#pragma unroll
    for (int it = 0; it < 4; ++it) {
        size_t g = (size_t)i0 + (size_t)it * 262144;  // 8-float groups, total 1048576
        const float4* s = (const float4*)(x + g * 8);
        float4 v0 = s[0], v1 = s[1];
        uint4 o;
        o.x = packbf(v0.x, v0.y); o.y = packbf(v0.z, v0.w);
        o.z = packbf(v1.x, v1.y); o.w = packbf(v1.z, v1.w);
        *(uint4*)(xbf + g * 8) = o;
    }
}

// ---------------------------------------------------------------------------
// k0a: lampow[j][n] = Lambda[n]^(j+1), j in [0,128)  (fp32 complex)
__global__ void k0a_lampow(const float* __restrict__ nu_log,
                           const float* __restrict__ theta_log,
                           float2* __restrict__ lampow) {
    int n = threadIdx.x;
    float lm = expf(-expf(nu_log[n]));
    float th = expf(theta_log[n]);
    float lr = lm * cosf(th), li = lm * sinf(th);
    float pr = lr, pi = li;
    for (int j = 0; j < CHUNK; ++j) {
        lampow[j * STATE_F + n] = make_float2(pr, pi);
        float t = fmaf(pr, lr, -pi * li);
        pi = fmaf(pr, li, pi * lr);
        pr = t;
    }
}

// ---------------------------------------------------------------------------
// k0b: pack W1 (512x128) A-fragments for k1.  Row n'=2n -> gamma*B_re[n],
// n'=2n+1 -> gamma*B_im[n].  Frag order: (mt,ks) -> lane l -> 8 bf16 with
// k = ks*32 + (l>>4)*8 + j,  n' = mt*16 + (l&15).
__global__ __launch_bounds__(256) void k0b_w1p(const float* __restrict__ B_re,
                                               const float* __restrict__ B_im,
                                               const float* __restrict__ gamma_log,
                                               unsigned short* __restrict__ W1p) {
    int tid = blockIdx.x * 256 + threadIdx.x;   // 0..8191
    int frag = tid >> 6, l = tid & 63;
    int mt = frag >> 2, ks = frag & 3;
    int np = mt * 16 + (l & 15);
    int k0 = ks * 32 + (l >> 4) * 8;
    int s = np >> 1;
    float g = expf(gamma_log[s]);
    const float* src = ((np & 1) ? B_im : B_re) + s * IN_F + k0;
    float4 a = *(const float4*)src, b = *(const float4*)(src + 4);
    uint4 o;
    o.x = packbf(a.x * g, a.y * g); o.y = packbf(a.z * g, a.w * g);
    o.z = packbf(b.x * g, b.y * g); o.w = packbf(b.z * g, b.w * g);
    *(uint4*)(W1p + (size_t)tid * 8) = o;
}

// ---------------------------------------------------------------------------
// k0c: pack W3 (128x640) B-fragments for k3: [C_re | -C_im | D].
// Frag order: (ct,ks) -> lane l: o = ct*16+(l&15), k = ks*32+(l>>4)*8+j.
__global__ __launch_bounds__(256) void k0c_w3p(const float* __restrict__ C_re,
                                               const float* __restrict__ C_im,
                                               const float* __restrict__ D,
                                               unsigned short* __restrict__ W3p) {
    int tid = blockIdx.x * 256 + threadIdx.x;   // 0..10239
    int frag = tid >> 6, l = tid & 63;
    int ct = frag / 20, ks = frag % 20;
    int o = ct * 16 + (l & 15);
    int k0 = ks * 32 + (l >> 4) * 8;
    const float* src;
    float sgn = 1.f;
    if (k0 < 256) src = C_re + o * STATE_F + k0;
    else if (k0 < 512) { src = C_im + o * STATE_F + (k0 - 256); sgn = -1.f; }
    else src = D + o * IN_F + (k0 - 512);
    float4 a = *(const float4*)src, b = *(const float4*)(src + 4);
    uint4 w;
    w.x = packbf(a.x * sgn, a.y * sgn); w.y = packbf(a.z * sgn, a.w * sgn);
    w.z = packbf(b.x * sgn, b.y * sgn); w.w = packbf(b.z * sgn, b.w * sgn);
    *(uint4*)(W3p + (size_t)tid * 8) = w;
}

// ---------------------------------------------------------------------------
// k1: transposed MFMA GEMM  D[n'][t] = sum_k W1[n'][k] * xbf[t][k].
// Block: 64 t-rows, full 512 n'.  Wave w: mt in [w*8,w*8+8), tt 0..3.
// Epilogue packs (re,im) bf16 pairs -> Bu[t][n] (uint per state).
__global__ __launch_bounds__(256, 2) void k1_bu(const short* __restrict__ xbf,
                                                const short* __restrict__ W1p,
                                                unsigned* __restrict__ Bu) {
    int tid = threadIdx.x;
    int wid = tid >> 6, l = tid & 63;
    int row0 = blockIdx.x * 64;
    const bf16x8* wp = (const bf16x8*)W1p;
    const bf16x8* xp = (const bf16x8*)xbf;

    f32x4 acc[8][4];
#pragma unroll
    for (int i = 0; i < 8; ++i)
#pragma unroll
        for (int t = 0; t < 4; ++t) acc[i][t] = (f32x4){0.f, 0.f, 0.f, 0.f};

#pragma unroll
    for (int ks = 0; ks < 4; ++ks) {
        bf16x8 b[4];
#pragma unroll
        for (int tt = 0; tt < 4; ++tt) {
            int t = row0 + tt * 16 + (l & 15);
            b[tt] = xp[(size_t)t * 16 + ks * 4 + (l >> 4)];
        }
#pragma unroll
        for (int i = 0; i < 8; ++i) {
            int mt = wid * 8 + i;
            bf16x8 a = wp[(size_t)(mt * 4 + ks) * 64 + l];
#pragma unroll
            for (int tt = 0; tt < 4; ++tt)
                acc[i][tt] = __builtin_amdgcn_mfma_f32_16x16x32_bf16(a, b[tt], acc[i][tt], 0, 0, 0);
        }
    }
    // epilogue: rows n' = mt*16 + (l>>4)*4 + r  ->  states n0=mt*8+(l>>4)*2, n0+1
#pragma unroll
    for (int i = 0; i < 8; ++i) {
        int n0 = (wid * 8 + i) * 8 + (l >> 4) * 2;
#pragma unroll
        for (int tt = 0; tt < 4; ++tt) {
            int t = row0 + tt * 16 + (l & 15);
            uint2 w;
            w.x = packbf(acc[i][tt][0], acc[i][tt][1]);  // re,im of n0
            w.y = packbf(acc[i][tt][2], acc[i][tt][3]);  // re,im of n0+1
            *(uint2*)(Bu + (size_t)t * STATE_F + n0) = w;
        }
    }
}

// ---------------------------------------------------------------------------
// k2a: in-place chunk scan on packed bf16 states (fp32 accumulator),
// records fp32 chunk-end states.
__global__ __launch_bounds__(256) void k2a_scan(const float* __restrict__ nu_log,
                                                const float* __restrict__ theta_log,
                                                unsigned* __restrict__ Bu,
                                                float2* __restrict__ ends) {
    int n = threadIdx.x;
    int b = blockIdx.x >> 6, c = blockIdx.x & 63;
    float lm = expf(-expf(nu_log[n]));
    float th = expf(theta_log[n]);
    float lr = lm * cosf(th), li = lm * sinf(th);
    float sr = 0.f, si = 0.f;
    unsigned* p = Bu + (((size_t)b * T + (size_t)c * CHUNK) * STATE_F + n);
#pragma unroll 8
    for (int j = 0; j < CHUNK; ++j) {
        unsigned u = p[(size_t)j * STATE_F];
        float br = bflo(u), bi = bfhi(u);
        float nr = fmaf(lr, sr, fmaf(-li, si, br));
        float ni = fmaf(lr, si, fmaf(li, sr, bi));
        sr = nr; si = ni;
        p[(size_t)j * STATE_F] = packbf(sr, si);
    }
    ends[((size_t)(b * NCHUNK + c)) * STATE_F + n] = make_float2(sr, si);
}

// ---------------------------------------------------------------------------
// k2b: scan over chunk-final states (Lambda^128 via 7 squarings), in place.
__global__ void k2b_chain(const float* __restrict__ nu_log,
                          const float* __restrict__ theta_log,
                          float2* __restrict__ ends) {
    int n = threadIdx.x;
    int b = blockIdx.x;
    float lm = expf(-expf(nu_log[n]));
    float th = expf(theta_log[n]);
    float Lr = lm * cosf(th), Li = lm * sinf(th);
#pragma unroll
    for (int i = 0; i < 7; ++i) {  // Lambda^128
        float t = Lr * Lr - Li * Li;
        Li = 2.f * Lr * Li;
        Lr = t;
    }
    float sr = 0.f, si = 0.f;
    float2* p = ends + (size_t)b * NCHUNK * STATE_F + n;
    for (int c = 0; c < NCHUNK; ++c) {
        float2 e = p[(size_t)c * STATE_F];
        float nr = fmaf(Lr, sr, fmaf(-Li, si, e.x));
        float ni = fmaf(Lr, si, fmaf(Li, sr, e.y));
        sr = nr; si = ni;
        p[(size_t)c * STATE_F] = make_float2(sr, si);
    }
}

// ---------------------------------------------------------------------------
// k3: fused fixup + output GEMM via MFMA.
// A (LDS, 32 rows x 640 bf16, XOR-swizzled 16B blocks) = [S_re | S_im | x].
// B = W3p prepacked.  out[t][o] fp32.
__global__ __launch_bounds__(256) void k3_out(const short* __restrict__ xbf,
                                              const short* __restrict__ W3p,
                                              const unsigned* __restrict__ Bu,
                                              const float2* __restrict__ ends,
                                              const float2* __restrict__ lampow,
                                              float* __restrict__ out) {
    __shared__ short A[32 * 640];  // 40 KB
    int tid = threadIdx.x;
    int l = tid & 63, wid = tid >> 6;
    int row0 = blockIdx.x * 32;
    int b = row0 >> 13;
    int t0 = row0 & (T - 1);
    int c = t0 >> 7;
    int j0 = t0 & (CHUNK - 1);

    // ---- stage x tile: cols 512..639 (16B blocks 64..79)
    const bf16x8* xp = (const bf16x8*)xbf;
#pragma unroll
    for (int i = 0; i < 2; ++i) {
        int idx = i * 256 + tid;
        int row = idx >> 4, seg = idx & 15;
        int blk = 64 + (seg ^ (row & 7));
        *(bf16x8*)&A[row * 640 + blk * 8] = xp[(size_t)(row0 + row) * 16 + seg];
    }
    // ---- stage states (fixup in fp32, split into re/im planes)
    {
        int half = tid >> 7, tn = tid & 127;
        int n0 = tn * 2;
        float c0r = 0.f, c0i = 0.f, c1r = 0.f, c1i = 0.f;
        if (c > 0) {
            float4 e = *(const float4*)&ends[((size_t)(b * NCHUNK + c - 1)) * STATE_F + n0];
            c0r = e.x; c0i = e.y; c1r = e.z; c1i = e.w;
        }
#pragma unroll 4
        for (int r8 = 0; r8 < 16; ++r8) {
            int r = half * 16 + r8;
            uint2 s2 = *(const uint2*)&Bu[(size_t)(row0 + r) * STATE_F + n0];
            float s0r = bflo(s2.x), s0i = bfhi(s2.x);
            float s1r = bflo(s2.y), s1i = bfhi(s2.y);
            if (c > 0) {
                float4 pw = *(const float4*)&lampow[(j0 + r) * STATE_F + n0];
                s0r = fmaf(pw.x, c0r, fmaf(-pw.y, c0i, s0r));
                s0i = fmaf(pw.x, c0i, fmaf(pw.y, c0r, s0i));
                s1r = fmaf(pw.z, c1r, fmaf(-pw.w, c1i, s1r));
                s1i = fmaf(pw.z, c1i, fmaf(pw.w, c1r, s1i));
            }
            int blk = (n0 >> 3) ^ (r & 7);
            int base = r * 640 + blk * 8 + (n0 & 7);
            *(unsigned*)&A[base] = packbf(s0r, s1r);             // re plane
            *(unsigned*)&A[base + 32 * 8] = packbf(s0i, s1i);    // im plane (+blocks 32)
        }
    }
    __syncthreads();

    // ---- GEMM: 20 ksteps, wave handles ct = {2w, 2w+1}, mt = 0..1
    const bf16x8* wp = (const bf16x8*)W3p;
    int ct0 = wid * 2;
    f32x4 acc[2][2];
#pragma unroll
    for (int m = 0; m < 2; ++m)
#pragma unroll
        for (int cc = 0; cc < 2; ++cc) acc[m][cc] = (f32x4){0.f, 0.f, 0.f, 0.f};

#pragma unroll 4
    for (int ks = 0; ks < 20; ++ks) {
        bf16x8 a[2];
#pragma unroll
        for (int m = 0; m < 2; ++m) {
            int r = m * 16 + (l & 15);
            int kb = ks * 4 + (l >> 4);
            int blk = kb ^ (r & 7);
            a[m] = *(const bf16x8*)&A[r * 640 + blk * 8];
        }
        bf16x8 bf[2];
#pragma unroll
        for (int cc = 0; cc < 2; ++cc)
            bf[cc] = wp[(size_t)((ct0 + cc) * 20 + ks) * 64 + l];
#pragma unroll
        for (int m = 0; m < 2; ++m)
#pragma unroll
            for (int cc = 0; cc < 2; ++cc)
                acc[m][cc] = __builtin_amdgcn_mfma_f32_16x16x32_bf16(a[m], bf[cc], acc[m][cc], 0, 0, 0);
    }
    // ---- epilogue
#pragma unroll
    for (int m = 0; m < 2; ++m)
#pragma unroll
        for (int cc = 0; cc < 2; ++cc)
#pragma unroll
            for (int r = 0; r < 4; ++r) {
                int t = row0 + m * 16 + (l >> 4) * 4 + r;
                int o = (ct0 + cc) * 16 + (l & 15);
                out[(size_t)t * OUT_F + o] = acc[m][cc][r];
            }
}

// ---------------------------------------------------------------------------
extern "C" void kernel_launch(void* const* d_in, const int* in_sizes, int n_in,
                              void* d_out, int out_size, void* d_ws, size_t ws_size,
                              hipStream_t stream) {
    const float* x         = (const float*)d_in[0];
    const float* nu_log    = (const float*)d_in[1];
    const float* theta_log = (const float*)d_in[2];
    const float* gamma_log = (const float*)d_in[3];
    const float* B_re      = (const float*)d_in[4];
    const float* B_im      = (const float*)d_in[5];
    const float* C_re      = (const float*)d_in[6];
    const float* C_im      = (const float*)d_in[7];
    const float* D         = (const float*)d_in[8];
    float* out = (float*)d_out;

    char* ws = (char*)d_ws;
    // layout (bytes):
    unsigned*       Bu     = (unsigned*)ws;                         // 67,108,864
    unsigned short* xbf    = (unsigned short*)(ws + 67108864);      // 16,777,216
    float2*         ends   = (float2*)(ws + 83886080);              //  1,048,576
    float2*         lampow = (float2*)(ws + 84934656);              //    262,144
    unsigned short* W1p    = (unsigned short*)(ws + 85196800);      //    131,072
    unsigned short* W3p    = (unsigned short*)(ws + 85327872);      //    163,840
    if (ws_size < (size_t)85491712) return;

    kcvt<<<1024, 256, 0, stream>>>(x, (unsigned short*)xbf);
    k0a_lampow<<<1, 256, 0, stream>>>(nu_log, theta_log, lampow);
    k0b_w1p<<<32, 256, 0, stream>>>(B_re, B_im, gamma_log, W1p);
    k0c_w3p<<<40, 256, 0, stream>>>(C_re, C_im, D, W3p);
    k1_bu<<<ROWS / 64, 256, 0, stream>>>((const short*)xbf, (const short*)W1p, Bu);
    k2a_scan<<<BATCH * NCHUNK, 256, 0, stream>>>(nu_log, theta_log, Bu, ends);
    k2b_chain<<<BATCH, 256, 0, stream>>>(nu_log, theta_log, ends);
    k3_out<<<ROWS / 32, 256, 0, stream>>>((const short*)xbf, (const short*)W3p,
                                          Bu, ends, lampow, out);
}

// Round 10
// 118.977 us; speedup vs baseline: 1.0388x; 1.0388x over previous
//
#include <hip/hip_runtime.h>
#include <hip/hip_bf16.h>

#define BATCH 8
#define T 8192
#define IN_F 128
#define OUT_F 128
#define STATE_F 256
#define CHUNK 128
#define NCHUNK 64
#define ROWS 65536

typedef __attribute__((ext_vector_type(8))) short bf16x8;
typedef __attribute__((ext_vector_type(4))) float f32x4;

__device__ __forceinline__ float bflo(unsigned u) { return __uint_as_float(u << 16); }
__device__ __forceinline__ float bfhi(unsigned u) { return __uint_as_float(u & 0xffff0000u); }
__device__ __forceinline__ unsigned f2bfu(float f) {
    unsigned u = __float_as_uint(f);
    return (u + 0x7fffu + ((u >> 16) & 1u)) >> 16;
}
__device__ __forceinline__ unsigned packbf(float lo, float hi) {
    return f2bfu(lo) | (f2bfu(hi) << 16);
}
// load 8 consecutive fp32, convert to a bf16x8 fragment (RNE, same as old kcvt)
__device__ __forceinline__ bf16x8 ld_xbf8(const float* p) {
    float4 a = *(const float4*)p, b = *(const float4*)(p + 4);
    union { uint4 u; bf16x8 v; } cv;
    cv.u.x = packbf(a.x, a.y); cv.u.y = packbf(a.z, a.w);
    cv.u.z = packbf(b.x, b.y); cv.u.w = packbf(b.z, b.w);
    return cv.v;
}

// ---------------------------------------------------------------------------
// k0a: lampow[j][n] = Lambda[n]^(j+1), j in [0,128)  (fp32 complex)
__global__ void k0a_lampow(const float* __restrict__ nu_log,
                           const float* __restrict__ theta_log,
                           float2* __restrict__ lampow) {
    int n = threadIdx.x;
    float lm = expf(-expf(nu_log[n]));
    float th = expf(theta_log[n]);
    float lr = lm * cosf(th), li = lm * sinf(th);
    float pr = lr, pi = li;
    for (int j = 0; j < CHUNK; ++j) {
        lampow[j * STATE_F + n] = make_float2(pr, pi);
        float t = fmaf(pr, lr, -pi * li);
        pi = fmaf(pr, li, pi * lr);
        pr = t;
    }
}

// ---------------------------------------------------------------------------
// k0b: pack W1 (512x128) A-fragments for k1.  Row n'=2n -> gamma*B_re[n],
// n'=2n+1 -> gamma*B_im[n].  Frag order: (mt,ks) -> lane l -> 8 bf16 with
// k = ks*32 + (l>>4)*8 + j,  n' = mt*16 + (l&15).
__global__ __launch_bounds__(256) void k0b_w1p(const float* __restrict__ B_re,
                                               const float* __restrict__ B_im,
                                               const float* __restrict__ gamma_log,
                                               unsigned short* __restrict__ W1p) {
    int tid = blockIdx.x * 256 + threadIdx.x;   // 0..8191
    int frag = tid >> 6, l = tid & 63;
    int mt = frag >> 2, ks = frag & 3;
    int np = mt * 16 + (l & 15);
    int k0 = ks * 32 + (l >> 4) * 8;
    int s = np >> 1;
    float g = expf(gamma_log[s]);
    const float* src = ((np & 1) ? B_im : B_re) + s * IN_F + k0;
    float4 a = *(const float4*)src, b = *(const float4*)(src + 4);
    uint4 o;
    o.x = packbf(a.x * g, a.y * g); o.y = packbf(a.z * g, a.w * g);
    o.z = packbf(b.x * g, b.y * g); o.w = packbf(b.z * g, b.w * g);
    *(uint4*)(W1p + (size_t)tid * 8) = o;
}

// ---------------------------------------------------------------------------
// k0c: pack W3 (128x640) B-fragments for k3: [C_re | -C_im | D].
// Frag order: (ct,ks) -> lane l: o = ct*16+(l&15), k = ks*32+(l>>4)*8+j.
__global__ __launch_bounds__(256) void k0c_w3p(const float* __restrict__ C_re,
                                               const float* __restrict__ C_im,
                                               const float* __restrict__ D,
                                               unsigned short* __restrict__ W3p) {
    int tid = blockIdx.x * 256 + threadIdx.x;   // 0..10239
    int frag = tid >> 6, l = tid & 63;
    int ct = frag / 20, ks = frag % 20;
    int o = ct * 16 + (l & 15);
    int k0 = ks * 32 + (l >> 4) * 8;
    const float* src;
    float sgn = 1.f;
    if (k0 < 256) src = C_re + o * STATE_F + k0;
    else if (k0 < 512) { src = C_im + o * STATE_F + (k0 - 256); sgn = -1.f; }
    else src = D + o * IN_F + (k0 - 512);
    float4 a = *(const float4*)src, b = *(const float4*)(src + 4);
    uint4 w;
    w.x = packbf(a.x * sgn, a.y * sgn); w.y = packbf(a.z * sgn, a.w * sgn);
    w.z = packbf(b.x * sgn, b.y * sgn); w.w = packbf(b.z * sgn, b.w * sgn);
    *(uint4*)(W3p + (size_t)tid * 8) = w;
}

// ---------------------------------------------------------------------------
// k1: transposed MFMA GEMM  D[n'][t] = sum_k W1[n'][k] * x_bf16[t][k].
// Identical to green round-2 k1_bu except B-fragments are converted from
// fp32 x on the fly (ld_xbf8: pure per-thread transform, same RNE rounding
// as the deleted kcvt -> bit-identical fragments).
__global__ __launch_bounds__(256, 2) void k1_bu(const float* __restrict__ x,
                                                const short* __restrict__ W1p,
                                                unsigned* __restrict__ Bu) {
    int tid = threadIdx.x;
    int wid = tid >> 6, l = tid & 63;
    int row0 = blockIdx.x * 64;
    const bf16x8* wp = (const bf16x8*)W1p;

    f32x4 acc[8][4];
#pragma unroll
    for (int i = 0; i < 8; ++i)
#pragma unroll
        for (int t = 0; t < 4; ++t) acc[i][t] = (f32x4){0.f, 0.f, 0.f, 0.f};

#pragma unroll
    for (int ks = 0; ks < 4; ++ks) {
        bf16x8 b[4];
#pragma unroll
        for (int tt = 0; tt < 4; ++tt) {
            int t = row0 + tt * 16 + (l & 15);
            b[tt] = ld_xbf8(x + (size_t)t * IN_F + (ks * 4 + (l >> 4)) * 8);
        }
#pragma unroll
        for (int i = 0; i < 8; ++i) {
            int mt = wid * 8 + i;
            bf16x8 a = wp[(size_t)(mt * 4 + ks) * 64 + l];
#pragma unroll
            for (int tt = 0; tt < 4; ++tt)
                acc[i][tt] = __builtin_amdgcn_mfma_f32_16x16x32_bf16(a, b[tt], acc[i][tt], 0, 0, 0);
        }
    }
    // epilogue: rows n' = mt*16 + (l>>4)*4 + r  ->  states n0=mt*8+(l>>4)*2, n0+1
#pragma unroll
    for (int i = 0; i < 8; ++i) {
        int n0 = (wid * 8 + i) * 8 + (l >> 4) * 2;
#pragma unroll
        for (int tt = 0; tt < 4; ++tt) {
            int t = row0 + tt * 16 + (l & 15);
            uint2 w;
            w.x = packbf(acc[i][tt][0], acc[i][tt][1]);  // re,im of n0
            w.y = packbf(acc[i][tt][2], acc[i][tt][3]);  // re,im of n0+1
            *(uint2*)(Bu + (size_t)t * STATE_F + n0) = w;
        }
    }
}

// ---------------------------------------------------------------------------
// k2a: in-place chunk scan on packed bf16 states (fp32 accumulator),
// records fp32 chunk-end states.  (round-2 verbatim)
__global__ __launch_bounds__(256) void k2a_scan(const float* __restrict__ nu_log,
                                                const float* __restrict__ theta_log,
                                                unsigned* __restrict__ Bu,
                                                float2* __restrict__ ends) {
    int n = threadIdx.x;
    int b = blockIdx.x >> 6, c = blockIdx.x & 63;
    float lm = expf(-expf(nu_log[n]));
    float th = expf(theta_log[n]);
    float lr = lm * cosf(th), li = lm * sinf(th);
    float sr = 0.f, si = 0.f;
    unsigned* p = Bu + (((size_t)b * T + (size_t)c * CHUNK) * STATE_F + n);
#pragma unroll 8
    for (int j = 0; j < CHUNK; ++j) {
        unsigned u = p[(size_t)j * STATE_F];
        float br = bflo(u), bi = bfhi(u);
        float nr = fmaf(lr, sr, fmaf(-li, si, br));
        float ni = fmaf(lr, si, fmaf(li, sr, bi));
        sr = nr; si = ni;
        p[(size_t)j * STATE_F] = packbf(sr, si);
    }
    ends[((size_t)(b * NCHUNK + c)) * STATE_F + n] = make_float2(sr, si);
}

// ---------------------------------------------------------------------------
// k2b: scan over chunk-final states (Lambda^128 via 7 squarings), in place.
__global__ void k2b_chain(const float* __restrict__ nu_log,
                          const float* __restrict__ theta_log,
                          float2* __restrict__ ends) {
    int n = threadIdx.x;
    int b = blockIdx.x;
    float lm = expf(-expf(nu_log[n]));
    float th = expf(theta_log[n]);
    float Lr = lm * cosf(th), Li = lm * sinf(th);
#pragma unroll
    for (int i = 0; i < 7; ++i) {  // Lambda^128
        float t = Lr * Lr - Li * Li;
        Li = 2.f * Lr * Li;
        Lr = t;
    }
    float sr = 0.f, si = 0.f;
    float2* p = ends + (size_t)b * NCHUNK * STATE_F + n;
    for (int c = 0; c < NCHUNK; ++c) {
        float2 e = p[(size_t)c * STATE_F];
        float nr = fmaf(Lr, sr, fmaf(-Li, si, e.x));
        float ni = fmaf(Lr, si, fmaf(Li, sr, e.y));
        sr = nr; si = ni;
        p[(size_t)c * STATE_F] = make_float2(sr, si);
    }
}

// ---------------------------------------------------------------------------
// k3: fused fixup + output GEMM via MFMA — 512-thread variant (green in
// round 3) with CHUNK=128 constants and fp32 x staging (per-thread
// transform into the same LDS slots as the green round-2 staging).
// A (LDS, 32 x 640 bf16, XOR-swizzled 16B blocks) = [S_re | S_im | x].
__global__ __launch_bounds__(512) void k3_out(const float* __restrict__ x,
                                              const short* __restrict__ W3p,
                                              const unsigned* __restrict__ Bu,
                                              const float2* __restrict__ ends,
                                              const float2* __restrict__ lampow,
                                              float* __restrict__ out) {
    __shared__ short A[32 * 640];  // 40 KB
    int tid = threadIdx.x;
    int l = tid & 63, wid = tid >> 6;
    int row0 = blockIdx.x * 32;
    int b = row0 >> 13;
    int t0 = row0 & (T - 1);
    int c = t0 >> 7;                 // CHUNK=128
    int j0 = t0 & (CHUNK - 1);

    // ---- preload all state pairs for this thread (async-split: loads first)
    int tn = tid & 127, grp = tid >> 7;
    int n0 = tn * 2;
    uint2 sv[8];
#pragma unroll
    for (int r8 = 0; r8 < 8; ++r8)
        sv[r8] = *(const uint2*)&Bu[(size_t)(row0 + grp * 8 + r8) * STATE_F + n0];

    // ---- stage x tile (fp32 -> bf16, swizzled): cols 512..639
    {
        int row = tid >> 4, seg = tid & 15;
        const float4* xp = (const float4*)(x + (size_t)(row0 + row) * IN_F + seg * 8);
        float4 a = xp[0], bb = xp[1];
        uint4 w;
        w.x = packbf(a.x, a.y); w.y = packbf(a.z, a.w);
        w.z = packbf(bb.x, bb.y); w.w = packbf(bb.z, bb.w);
        *(uint4*)&A[row * 640 + (64 + (seg ^ (row & 7))) * 8] = w;
    }

    // ---- fixup + write state planes
    {
        float c0r = 0.f, c0i = 0.f, c1r = 0.f, c1i = 0.f;
        if (c > 0) {
            float4 e = *(const float4*)&ends[((size_t)(b * NCHUNK + c - 1)) * STATE_F + n0];
            c0r = e.x; c0i = e.y; c1r = e.z; c1i = e.w;
        }
#pragma unroll
        for (int r8 = 0; r8 < 8; ++r8) {
            int r = grp * 8 + r8;
            float s0r = bflo(sv[r8].x), s0i = bfhi(sv[r8].x);
            float s1r = bflo(sv[r8].y), s1i = bfhi(sv[r8].y);
            if (c > 0) {
                float4 pw = *(const float4*)&lampow[(j0 + r) * STATE_F + n0];
                s0r = fmaf(pw.x, c0r, fmaf(-pw.y, c0i, s0r));
                s0i = fmaf(pw.x, c0i, fmaf(pw.y, c0r, s0i));
                s1r = fmaf(pw.z, c1r, fmaf(-pw.w, c1i, s1r));
                s1i = fmaf(pw.z, c1i, fmaf(pw.w, c1r, s1i));
            }
            int blk = (n0 >> 3) ^ (r & 7);
            int base = r * 640 + blk * 8 + (n0 & 7);
            *(unsigned*)&A[base] = packbf(s0r, s1r);         // re plane
            *(unsigned*)&A[base + 256] = packbf(s0i, s1i);   // im plane (+32 blocks)
        }
    }
    __syncthreads();

    // ---- GEMM: wave wid -> ct = wid (out cols wid*16..+16), m = 0..1
    const bf16x8* wp = (const bf16x8*)W3p;
    int ct = wid;
    f32x4 acc[2];
    acc[0] = (f32x4){0.f, 0.f, 0.f, 0.f};
    acc[1] = (f32x4){0.f, 0.f, 0.f, 0.f};

#pragma unroll 4
    for (int ks = 0; ks < 20; ++ks) {
        bf16x8 bf = wp[(size_t)(ct * 20 + ks) * 64 + l];
#pragma unroll
        for (int m = 0; m < 2; ++m) {
            int rr = m * 16 + (l & 15);
            int kb = ks * 4 + (l >> 4);
            bf16x8 am = *(const bf16x8*)&A[rr * 640 + (kb ^ (rr & 7)) * 8];
            acc[m] = __builtin_amdgcn_mfma_f32_16x16x32_bf16(am, bf, acc[m], 0, 0, 0);
        }
    }
    // ---- epilogue
#pragma unroll
    for (int m = 0; m < 2; ++m)
#pragma unroll
        for (int r = 0; r < 4; ++r) {
            int t = row0 + m * 16 + (l >> 4) * 4 + r;
            int o = ct * 16 + (l & 15);
            out[(size_t)t * OUT_F + o] = acc[m][r];
        }
}

// ---------------------------------------------------------------------------
extern "C" void kernel_launch(void* const* d_in, const int* in_sizes, int n_in,
                              void* d_out, int out_size, void* d_ws, size_t ws_size,
                              hipStream_t stream) {
    const float* x         = (const float*)d_in[0];
    const float* nu_log    = (const float*)d_in[1];
    const float* theta_log = (const float*)d_in[2];
    const float* gamma_log = (const float*)d_in[3];
    const float* B_re      = (const float*)d_in[4];
    const float* B_im      = (const float*)d_in[5];
    const float* C_re      = (const float*)d_in[6];
    const float* C_im      = (const float*)d_in[7];
    const float* D         = (const float*)d_in[8];
    float* out = (float*)d_out;

    char* ws = (char*)d_ws;
    // layout (bytes):
    unsigned*       Bu     = (unsigned*)ws;                         // 67,108,864
    float2*         ends   = (float2*)(ws + 67108864);              //  1,048,576
    float2*         lampow = (float2*)(ws + 68157440);              //    262,144
    unsigned short* W1p    = (unsigned short*)(ws + 68419584);      //    131,072
    unsigned short* W3p    = (unsigned short*)(ws + 68550656);      //    163,840
    if (ws_size < (size_t)68714496) return;

    k0a_lampow<<<1, 256, 0, stream>>>(nu_log, theta_log, lampow);
    k0b_w1p<<<32, 256, 0, stream>>>(B_re, B_im, gamma_log, W1p);
    k0c_w3p<<<40, 256, 0, stream>>>(C_re, C_im, D, W3p);
    k1_bu<<<ROWS / 64, 256, 0, stream>>>(x, (const short*)W1p, Bu);
    k2a_scan<<<BATCH * NCHUNK, 256, 0, stream>>>(nu_log, theta_log, Bu, ends);
    k2b_chain<<<BATCH, 256, 0, stream>>>(nu_log, theta_log, ends);
    k3_out<<<ROWS / 32, 512, 0, stream>>>(x, (const short*)W3p, Bu, ends, lampow, out);
}

// Round 11
// 104.770 us; speedup vs baseline: 1.1796x; 1.1356x over previous
//
#include <hip/hip_runtime.h>
#include <hip/hip_bf16.h>

#define BATCH 8
#define T 8192
#define IN_F 128
#define OUT_F 128
#define STATE_F 256
#define CHUNK 128
#define NCHUNK 64
#define ROWS 65536

typedef __attribute__((ext_vector_type(8))) short bf16x8;
typedef __attribute__((ext_vector_type(4))) float f32x4;

__device__ __forceinline__ float bflo(unsigned u) { return __uint_as_float(u << 16); }
__device__ __forceinline__ float bfhi(unsigned u) { return __uint_as_float(u & 0xffff0000u); }
__device__ __forceinline__ unsigned f2bfu(float f) {
    unsigned u = __float_as_uint(f);
    return (u + 0x7fffu + ((u >> 16) & 1u)) >> 16;
}
__device__ __forceinline__ unsigned packbf(float lo, float hi) {
    return f2bfu(lo) | (f2bfu(hi) << 16);
}

// ---------------------------------------------------------------------------
// k0a: lampow[j][n] = Lambda[n]^(j+1), j in [0,128)  (fp32 complex)
__global__ void k0a_lampow(const float* __restrict__ nu_log,
                           const float* __restrict__ theta_log,
                           float2* __restrict__ lampow) {
    int n = threadIdx.x;
    float lm = expf(-expf(nu_log[n]));
    float th = expf(theta_log[n]);
    float lr = lm * cosf(th), li = lm * sinf(th);
    float pr = lr, pi = li;
    for (int j = 0; j < CHUNK; ++j) {
        lampow[j * STATE_F + n] = make_float2(pr, pi);
        float t = fmaf(pr, lr, -pi * li);
        pi = fmaf(pr, li, pi * lr);
        pr = t;
    }
}

// ---------------------------------------------------------------------------
// k0b: pack W1 (512x128) A-fragments for k1.  Row n'=2n -> gamma*B_re[n],
// n'=2n+1 -> gamma*B_im[n].  Frag order: (mt,ks) -> lane l -> 8 bf16 with
// k = ks*32 + (l>>4)*8 + j,  n' = mt*16 + (l&15).
__global__ __launch_bounds__(256) void k0b_w1p(const float* __restrict__ B_re,
                                               const float* __restrict__ B_im,
                                               const float* __restrict__ gamma_log,
                                               unsigned short* __restrict__ W1p) {
    int tid = blockIdx.x * 256 + threadIdx.x;   // 0..8191
    int frag = tid >> 6, l = tid & 63;
    int mt = frag >> 2, ks = frag & 3;
    int np = mt * 16 + (l & 15);
    int k0 = ks * 32 + (l >> 4) * 8;
    int s = np >> 1;
    float g = expf(gamma_log[s]);
    const float* src = ((np & 1) ? B_im : B_re) + s * IN_F + k0;
    float4 a = *(const float4*)src, b = *(const float4*)(src + 4);
    uint4 o;
    o.x = packbf(a.x * g, a.y * g); o.y = packbf(a.z * g, a.w * g);
    o.z = packbf(b.x * g, b.y * g); o.w = packbf(b.z * g, b.w * g);
    *(uint4*)(W1p + (size_t)tid * 8) = o;
}

// ---------------------------------------------------------------------------
// k0c: pack W3 (128x640) B-fragments for k3: [C_re | -C_im | D].
// Frag order: (ct,ks) -> lane l: o = ct*16+(l&15), k = ks*32+(l>>4)*8+j.
__global__ __launch_bounds__(256) void k0c_w3p(const float* __restrict__ C_re,
                                               const float* __restrict__ C_im,
                                               const float* __restrict__ D,
                                               unsigned short* __restrict__ W3p) {
    int tid = blockIdx.x * 256 + threadIdx.x;   // 0..10239
    int frag = tid >> 6, l = tid & 63;
    int ct = frag / 20, ks = frag % 20;
    int o = ct * 16 + (l & 15);
    int k0 = ks * 32 + (l >> 4) * 8;
    const float* src;
    float sgn = 1.f;
    if (k0 < 256) src = C_re + o * STATE_F + k0;
    else if (k0 < 512) { src = C_im + o * STATE_F + (k0 - 256); sgn = -1.f; }
    else src = D + o * IN_F + (k0 - 512);
    float4 a = *(const float4*)src, b = *(const float4*)(src + 4);
    uint4 w;
    w.x = packbf(a.x * sgn, a.y * sgn); w.y = packbf(a.z * sgn, a.w * sgn);
    w.z = packbf(b.x * sgn, b.y * sgn); w.w = packbf(b.z * sgn, b.w * sgn);
    *(uint4*)(W3p + (size_t)tid * 8) = w;
}

// ---------------------------------------------------------------------------
// k1n: transposed MFMA GEMM  D[n'][t] = sum_k W1[n'][k] * x_bf16[t][k],
// with x staged ONCE per block into LDS (swizzled write -> barrier ->
// swizzled bf16x8 read: the same pattern class as green k3_out staging).
// 512 threads (8 waves); wave wid covers mt = wid*4 .. wid*4+3 (acc[4][4]).
// Epilogue = round-2 green global Bu write (uint2 per state pair).
__global__ __launch_bounds__(512, 4) void k1n(const float* __restrict__ x,
                                              const short* __restrict__ W1p,
                                              unsigned* __restrict__ Bu) {
    __shared__ short XT[64 * IN_F];  // 16 KB
    int tid = threadIdx.x;
    int l = tid & 63, wid = tid >> 6;
    int row0 = blockIdx.x * 64;

    // ---- Phase A: stage x tile (fp32 -> bf16, each element converted once)
    {
        int row = tid >> 3, seg = tid & 7;   // 64 rows x 8 segs of 16 floats
        const float4* xp = (const float4*)(x + (size_t)(row0 + row) * IN_F + seg * 16);
        float4 a = xp[0], b = xp[1], c2 = xp[2], d = xp[3];
        uint4 w0, w1;
        w0.x = packbf(a.x, a.y); w0.y = packbf(a.z, a.w);
        w0.z = packbf(b.x, b.y); w0.w = packbf(b.z, b.w);
        w1.x = packbf(c2.x, c2.y); w1.y = packbf(c2.z, c2.w);
        w1.z = packbf(d.x, d.y);  w1.w = packbf(d.z, d.w);
        short* dst = XT + row * IN_F;
        *(uint4*)(dst + ((seg * 2) ^ (row & 7)) * 8) = w0;
        *(uint4*)(dst + ((seg * 2 + 1) ^ (row & 7)) * 8) = w1;
    }
    __syncthreads();

    // ---- Phase B: GEMM (wave wid: mt = wid*4+i)
    const bf16x8* wp = (const bf16x8*)W1p;
    f32x4 acc[4][4];
#pragma unroll
    for (int i = 0; i < 4; ++i)
#pragma unroll
        for (int tt = 0; tt < 4; ++tt) acc[i][tt] = (f32x4){0.f, 0.f, 0.f, 0.f};

#pragma unroll
    for (int ks = 0; ks < 4; ++ks) {
        bf16x8 b[4];
#pragma unroll
        for (int tt = 0; tt < 4; ++tt) {
            int row = tt * 16 + (l & 15);
            int kb = ks * 4 + (l >> 4);
            b[tt] = *(const bf16x8*)&XT[row * IN_F + ((kb ^ (row & 7)) << 3)];
        }
#pragma unroll
        for (int i = 0; i < 4; ++i) {
            bf16x8 a = wp[(size_t)((wid * 4 + i) * 4 + ks) * 64 + l];
#pragma unroll
            for (int tt = 0; tt < 4; ++tt)
                acc[i][tt] = __builtin_amdgcn_mfma_f32_16x16x32_bf16(a, b[tt], acc[i][tt], 0, 0, 0);
        }
    }
    // ---- epilogue: rows n' = mt*16+(l>>4)*4+r -> states n0 = mt*8+(l>>4)*2
#pragma unroll
    for (int i = 0; i < 4; ++i) {
        int n0 = (wid * 4 + i) * 8 + (l >> 4) * 2;
#pragma unroll
        for (int tt = 0; tt < 4; ++tt) {
            int t = row0 + tt * 16 + (l & 15);
            uint2 w;
            w.x = packbf(acc[i][tt][0], acc[i][tt][1]);  // re,im of n0
            w.y = packbf(acc[i][tt][2], acc[i][tt][3]);  // re,im of n0+1
            *(uint2*)(Bu + (size_t)t * STATE_F + n0) = w;
        }
    }
}

// ---------------------------------------------------------------------------
// k2a: in-place chunk scan on packed bf16 states (fp32 accumulator),
// records fp32 chunk-end states.  (round-2 verbatim)
__global__ __launch_bounds__(256) void k2a_scan(const float* __restrict__ nu_log,
                                                const float* __restrict__ theta_log,
                                                unsigned* __restrict__ Bu,
                                                float2* __restrict__ ends) {
    int n = threadIdx.x;
    int b = blockIdx.x >> 6, c = blockIdx.x & 63;
    float lm = expf(-expf(nu_log[n]));
    float th = expf(theta_log[n]);
    float lr = lm * cosf(th), li = lm * sinf(th);
    float sr = 0.f, si = 0.f;
    unsigned* p = Bu + (((size_t)b * T + (size_t)c * CHUNK) * STATE_F + n);
#pragma unroll 8
    for (int j = 0; j < CHUNK; ++j) {
        unsigned u = p[(size_t)j * STATE_F];
        float br = bflo(u), bi = bfhi(u);
        float nr = fmaf(lr, sr, fmaf(-li, si, br));
        float ni = fmaf(lr, si, fmaf(li, sr, bi));
        sr = nr; si = ni;
        p[(size_t)j * STATE_F] = packbf(sr, si);
    }
    ends[((size_t)(b * NCHUNK + c)) * STATE_F + n] = make_float2(sr, si);
}

// ---------------------------------------------------------------------------
// k2b: scan over chunk-final states (Lambda^128 via 7 squarings), in place.
__global__ void k2b_chain(const float* __restrict__ nu_log,
                          const float* __restrict__ theta_log,
                          float2* __restrict__ ends) {
    int n = threadIdx.x;
    int b = blockIdx.x;
    float lm = expf(-expf(nu_log[n]));
    float th = expf(theta_log[n]);
    float Lr = lm * cosf(th), Li = lm * sinf(th);
#pragma unroll
    for (int i = 0; i < 7; ++i) {  // Lambda^128
        float t = Lr * Lr - Li * Li;
        Li = 2.f * Lr * Li;
        Lr = t;
    }
    float sr = 0.f, si = 0.f;
    float2* p = ends + (size_t)b * NCHUNK * STATE_F + n;
    for (int c = 0; c < NCHUNK; ++c) {
        float2 e = p[(size_t)c * STATE_F];
        float nr = fmaf(Lr, sr, fmaf(-Li, si, e.x));
        float ni = fmaf(Lr, si, fmaf(Li, sr, e.y));
        sr = nr; si = ni;
        p[(size_t)c * STATE_F] = make_float2(sr, si);
    }
}

// ---------------------------------------------------------------------------
// k3: fused fixup + output GEMM via MFMA — 512-thread variant (green rounds
// 3 & 10), CHUNK=128 constants, fp32 x staging.
// A (LDS, 32 x 640 bf16, XOR-swizzled 16B blocks) = [S_re | S_im | x].
__global__ __launch_bounds__(512) void k3_out(const float* __restrict__ x,
                                              const short* __restrict__ W3p,
                                              const unsigned* __restrict__ Bu,
                                              const float2* __restrict__ ends,
                                              const float2* __restrict__ lampow,
                                              float* __restrict__ out) {
    __shared__ short A[32 * 640];  // 40 KB
    int tid = threadIdx.x;
    int l = tid & 63, wid = tid >> 6;
    int row0 = blockIdx.x * 32;
    int b = row0 >> 13;
    int t0 = row0 & (T - 1);
    int c = t0 >> 7;                 // CHUNK=128
    int j0 = t0 & (CHUNK - 1);

    // ---- preload all state pairs for this thread (async-split: loads first)
    int tn = tid & 127, grp = tid >> 7;
    int n0 = tn * 2;
    uint2 sv[8];
#pragma unroll
    for (int r8 = 0; r8 < 8; ++r8)
        sv[r8] = *(const uint2*)&Bu[(size_t)(row0 + grp * 8 + r8) * STATE_F + n0];

    // ---- stage x tile (fp32 -> bf16, swizzled): cols 512..639
    {
        int row = tid >> 4, seg = tid & 15;
        const float4* xp = (const float4*)(x + (size_t)(row0 + row) * IN_F + seg * 8);
        float4 a = xp[0], bb = xp[1];
        uint4 w;
        w.x = packbf(a.x, a.y); w.y = packbf(a.z, a.w);
        w.z = packbf(bb.x, bb.y); w.w = packbf(bb.z, bb.w);
        *(uint4*)&A[row * 640 + (64 + (seg ^ (row & 7))) * 8] = w;
    }

    // ---- fixup + write state planes
    {
        float c0r = 0.f, c0i = 0.f, c1r = 0.f, c1i = 0.f;
        if (c > 0) {
            float4 e = *(const float4*)&ends[((size_t)(b * NCHUNK + c - 1)) * STATE_F + n0];
            c0r = e.x; c0i = e.y; c1r = e.z; c1i = e.w;
        }
#pragma unroll
        for (int r8 = 0; r8 < 8; ++r8) {
            int r = grp * 8 + r8;
            float s0r = bflo(sv[r8].x), s0i = bfhi(sv[r8].x);
            float s1r = bflo(sv[r8].y), s1i = bfhi(sv[r8].y);
            if (c > 0) {
                float4 pw = *(const float4*)&lampow[(j0 + r) * STATE_F + n0];
                s0r = fmaf(pw.x, c0r, fmaf(-pw.y, c0i, s0r));
                s0i = fmaf(pw.x, c0i, fmaf(pw.y, c0r, s0i));
                s1r = fmaf(pw.z, c1r, fmaf(-pw.w, c1i, s1r));
                s1i = fmaf(pw.z, c1i, fmaf(pw.w, c1r, s1i));
            }
            int blk = (n0 >> 3) ^ (r & 7);
            int base = r * 640 + blk * 8 + (n0 & 7);
            *(unsigned*)&A[base] = packbf(s0r, s1r);         // re plane
            *(unsigned*)&A[base + 256] = packbf(s0i, s1i);   // im plane (+32 blocks)
        }
    }
    __syncthreads();

    // ---- GEMM: wave wid -> ct = wid (out cols wid*16..+16), m = 0..1
    const bf16x8* wp = (const bf16x8*)W3p;
    int ct = wid;
    f32x4 acc[2];
    acc[0] = (f32x4){0.f, 0.f, 0.f, 0.f};
    acc[1] = (f32x4){0.f, 0.f, 0.f, 0.f};

#pragma unroll 4
    for (int ks = 0; ks < 20; ++ks) {
        bf16x8 bf = wp[(size_t)(ct * 20 + ks) * 64 + l];
#pragma unroll
        for (int m = 0; m < 2; ++m) {
            int rr = m * 16 + (l & 15);
            int kb = ks * 4 + (l >> 4);
            bf16x8 am = *(const bf16x8*)&A[rr * 640 + (kb ^ (rr & 7)) * 8];
            acc[m] = __builtin_amdgcn_mfma_f32_16x16x32_bf16(am, bf, acc[m], 0, 0, 0);
        }
    }
    // ---- epilogue
#pragma unroll
    for (int m = 0; m < 2; ++m)
#pragma unroll
        for (int r = 0; r < 4; ++r) {
            int t = row0 + m * 16 + (l >> 4) * 4 + r;
            int o = ct * 16 + (l & 15);
            out[(size_t)t * OUT_F + o] = acc[m][r];
        }
}

// ---------------------------------------------------------------------------
extern "C" void kernel_launch(void* const* d_in, const int* in_sizes, int n_in,
                              void* d_out, int out_size, void* d_ws, size_t ws_size,
                              hipStream_t stream) {
    const float* x         = (const float*)d_in[0];
    const float* nu_log    = (const float*)d_in[1];
    const float* theta_log = (const float*)d_in[2];
    const float* gamma_log = (const float*)d_in[3];
    const float* B_re      = (const float*)d_in[4];
    const float* B_im      = (const float*)d_in[5];
    const float* C_re      = (const float*)d_in[6];
    const float* C_im      = (const float*)d_in[7];
    const float* D         = (const float*)d_in[8];
    float* out = (float*)d_out;

    char* ws = (char*)d_ws;
    // layout (bytes):
    unsigned*       Bu     = (unsigned*)ws;                         // 67,108,864
    float2*         ends   = (float2*)(ws + 67108864);              //  1,048,576
    float2*         lampow = (float2*)(ws + 68157440);              //    262,144
    unsigned short* W1p    = (unsigned short*)(ws + 68419584);      //    131,072
    unsigned short* W3p    = (unsigned short*)(ws + 68550656);      //    163,840
    if (ws_size < (size_t)68714496) return;

    k0a_lampow<<<1, 256, 0, stream>>>(nu_log, theta_log, lampow);
    k0b_w1p<<<32, 256, 0, stream>>>(B_re, B_im, gamma_log, W1p);
    k0c_w3p<<<40, 256, 0, stream>>>(C_re, C_im, D, W3p);
    k1n<<<ROWS / 64, 512, 0, stream>>>(x, (const short*)W1p, Bu);
    k2a_scan<<<BATCH * NCHUNK, 256, 0, stream>>>(nu_log, theta_log, Bu, ends);
    k2b_chain<<<BATCH, 256, 0, stream>>>(nu_log, theta_log, ends);
    k3_out<<<ROWS / 32, 512, 0, stream>>>(x, (const short*)W3p, Bu, ends, lampow, out);
}